// Round 7
// baseline (165.079 us; speedup 1.0000x reference)
//
#include <hip/hip_runtime.h>
#include <hip/hip_bf16.h>

#define T_NODES (64 * 2048)   // G*N = 131072
#define CIN 64
#define HC 128                // HEADS * C_OUT
#define NEG_SLOPE 0.2f
#define GEMM_BLOCKS (T_NODES / 64)   // BM=64 -> 2048 blocks

typedef unsigned short ushort_t;
typedef __attribute__((ext_vector_type(8))) short bf16x8;
typedef __attribute__((ext_vector_type(4))) float f32x4;
typedef __attribute__((ext_vector_type(2))) float f32x2;

__device__ __forceinline__ ushort_t f2bf(float x) {
    unsigned u = __float_as_uint(x);
    u += 0x7fffu + ((u >> 16) & 1u);   // RNE
    return (ushort_t)(u >> 16);
}
__device__ __forceinline__ float bf2f(ushort_t b) {
    return __uint_as_float(((unsigned)b) << 16);
}
// unpack a u32 holding 2 bf16 (lo = even channel) into f32x2
__device__ __forceinline__ f32x2 bf2x2(unsigned w) {
    f32x2 r;
    r.x = __uint_as_float(w << 16);
    r.y = __uint_as_float(w & 0xffff0000u);
    return r;
}
__device__ __forceinline__ f32x2 pkmax(f32x2 a, f32x2 b) {
    f32x2 r; r.x = fmaxf(a.x, b.x); r.y = fmaxf(a.y, b.y); return r;
}

// ---- Kernel 1: fused one-time prep: W transpose/bf16/swizzle + zero counts+flags ----
__global__ __launch_bounds__(256) void prep_init(const float* __restrict__ Wl,
                                                 const float* __restrict__ Wr,
                                                 uint4* __restrict__ wt,
                                                 unsigned* __restrict__ counts,
                                                 unsigned* __restrict__ partials) {
    const int bid = blockIdx.x, tid = threadIdx.x;
    if (bid < 8) {
        const int t = bid * 256 + tid;   // 0..2047
        const int n = t & 255, cc = t >> 8;
        const float* Wsrc = ((n < HC) ? Wl : Wr) + (n & (HC - 1));
        union { ushort_t u[8]; uint4 v; } pk;
#pragma unroll
        for (int j = 0; j < 8; ++j) pk.u[j] = f2bf(Wsrc[(cc * 8 + j) * HC]);
        const int sw = (n & 7) << 4;
        *(uint4*)((char*)wt + n * 128 + ((cc * 16) ^ sw)) = pk.v;
        if (bid == 0 && tid < 128) partials[tid] = 0u;   // lookback flags
    } else {
        const int i = (bid - 8) * 256 + tid;             // 0..16383
        uint4* c4 = (uint4*)counts;
        c4[i * 2]     = (uint4){0, 0, 0, 0};
        c4[i * 2 + 1] = (uint4){0, 0, 0, 0};
    }
}

// ---- Kernel 2: MFMA gemm (xl = x@W_l, xr = x@W_r, bf16 out) + fused dst-histogram ----
__global__ __launch_bounds__(256) void gemm_hist(const float* __restrict__ x,
                                                 const uint4* __restrict__ wt,
                                                 ushort_t* __restrict__ xl,
                                                 ushort_t* __restrict__ xr,
                                                 const int* __restrict__ ei,
                                                 unsigned* __restrict__ counts,
                                                 ushort_t* __restrict__ rank,
                                                 int E, int ET, int histBlocks) {
    __shared__ uint4 lds4[2560];   // 40 KB: xs[64][64]bf16 (8KB) + wsT[256][64]bf16 (32KB)
    const int tid = threadIdx.x;

    if (blockIdx.x < histBlocks) {
        const int b = blockIdx.x;
#pragma unroll
        for (int e = 0; e < 4; ++e) {
            int i = b * 1024 + e * 256 + tid;
            if (i < ET) {
                int dst = (i < E) ? ei[E + i] : (i - E);
                rank[i] = (ushort_t)atomicAdd(&counts[dst], 1u);
            }
        }
        return;
    }

    char* abase = (char*)lds4;          // xs: row r (0..63), 128B/row, XOR-swizzled
    char* wbase = (char*)lds4 + 8192;   // wsT: row n (0..255), 128B/row (k-contiguous)
    const int row0 = (blockIdx.x - histBlocks) * 64;

    {
        const int r = tid >> 2, c4 = tid & 3;
        const float4* xp = (const float4*)(x + (size_t)(row0 + r) * CIN + c4 * 16);
        float4 f0 = xp[0], f1 = xp[1], f2 = xp[2], f3 = xp[3];
        union { ushort_t u[16]; uint4 v[2]; } pk;
        const float s[16] = {f0.x,f0.y,f0.z,f0.w, f1.x,f1.y,f1.z,f1.w,
                             f2.x,f2.y,f2.z,f2.w, f3.x,f3.y,f3.z,f3.w};
#pragma unroll
        for (int j = 0; j < 16; ++j) pk.u[j] = f2bf(s[j]);
        const int sw = (r & 7) << 4;
        *(uint4*)(abase + r * 128 + ((c4 * 32)      ^ sw)) = pk.v[0];
        *(uint4*)(abase + r * 128 + ((c4 * 32 + 16) ^ sw)) = pk.v[1];
    }
    {
#pragma unroll
        for (int q = 0; q < 8; ++q)
            lds4[512 + q * 256 + tid] = wt[q * 256 + tid];
    }
    __syncthreads();

    const int wave = tid >> 6;
    const int lane = tid & 63;
    const int ar = lane & 15;
    const int kb = lane >> 4;

    bf16x8 afr[2][4], bfr[2][4];
#pragma unroll
    for (int kk = 0; kk < 2; ++kk) {
#pragma unroll
        for (int rt = 0; rt < 4; ++rt) {
            const int r = rt * 16 + ar;
            afr[kk][rt] = *(bf16x8*)(abase + r * 128 + ((kk * 64 + kb * 16) ^ ((r & 7) << 4)));
        }
#pragma unroll
        for (int ct = 0; ct < 4; ++ct) {
            const int n = wave * 64 + ct * 16 + ar;
            bfr[kk][ct] = *(bf16x8*)(wbase + n * 128 + ((kk * 64 + kb * 16) ^ ((n & 7) << 4)));
        }
    }

    f32x4 acc[4][4];
#pragma unroll
    for (int rt = 0; rt < 4; ++rt)
#pragma unroll
        for (int ct = 0; ct < 4; ++ct) acc[rt][ct] = (f32x4){0.f, 0.f, 0.f, 0.f};

#pragma unroll
    for (int kk = 0; kk < 2; ++kk)
#pragma unroll
        for (int rt = 0; rt < 4; ++rt)
#pragma unroll
            for (int ct = 0; ct < 4; ++ct)
                acc[rt][ct] = __builtin_amdgcn_mfma_f32_16x16x32_bf16(
                    afr[kk][rt], bfr[kk][ct], acc[rt][ct], 0, 0, 0);

    // C/D layout (verified): col = lane&15, row = (lane>>4)*4 + reg
    ushort_t* op = (wave < 2) ? xl : xr;
    const int colbase = (wave & 1) * 64 + ar;
    const int rowoff = (lane >> 4) * 4;
#pragma unroll
    for (int rt = 0; rt < 4; ++rt)
#pragma unroll
        for (int ct = 0; ct < 4; ++ct)
#pragma unroll
            for (int j = 0; j < 4; ++j)
                op[(size_t)(row0 + rt * 16 + rowoff + j) * HC + colbase + ct * 16] =
                    f2bf(acc[rt][ct][j]);
}

// ---- Kernel 3: single-pass scan (tile scan + publish-flag lookback) ----
// 128 blocks, all co-resident; partials zeroed by prep_init each call.
__global__ __launch_bounds__(256) void scan_all(const unsigned* __restrict__ counts,
                                                unsigned* __restrict__ offs,
                                                unsigned* __restrict__ partials) {
    __shared__ unsigned s[256];
    __shared__ unsigned wsum[4];
    const int b = blockIdx.x, t = threadIdx.x;
    const int base_i = b * 1024 + t * 4;
    uint4 c = *(const uint4*)(counts + base_i);
    unsigned mysum = c.x + c.y + c.z + c.w;
    s[t] = mysum;
    __syncthreads();
    for (int off = 1; off < 256; off <<= 1) {
        unsigned v = (t >= off) ? s[t - off] : 0u;
        __syncthreads();
        s[t] += v;
        __syncthreads();
    }
    const unsigned excl = s[t] - mysum;
    if (t == 255)
        __hip_atomic_store(&partials[b], s[255] | 0x80000000u,
                           __ATOMIC_RELEASE, __HIP_MEMORY_SCOPE_AGENT);
    // lookback: thread t polls tile t (< b)
    unsigned bs = 0;
    if (t < b) {
        unsigned v;
        do {
            v = __hip_atomic_load(&partials[t], __ATOMIC_ACQUIRE,
                                  __HIP_MEMORY_SCOPE_AGENT);
        } while (!(v & 0x80000000u));
        bs = v & 0x7fffffffu;
    }
#pragma unroll
    for (int off = 32; off; off >>= 1) bs += __shfl_xor(bs, off);
    if ((t & 63) == 0) wsum[t >> 6] = bs;
    __syncthreads();
    const unsigned base = wsum[0] + wsum[1] + wsum[2] + wsum[3];
    uint4 o;
    o.x = excl + base;
    o.y = o.x + c.x;
    o.z = o.y + c.y;
    o.w = o.z + c.z;
    *(uint4*)(offs + base_i) = o;
}

// ---- Kernel 4: scatter src ids into dst-sorted order (atomic-free) ----
__global__ void scatter_edges(const int* __restrict__ ei,
                              const unsigned* __restrict__ offs,
                              const ushort_t* __restrict__ rank,
                              int* __restrict__ sorted_src, int E, int ET) {
    int i = blockIdx.x * 256 + threadIdx.x;
    if (i >= ET) return;
    int src, dst;
    if (i < E) { src = ei[i]; dst = ei[E + i]; }
    else       { src = dst = i - E; }
    sorted_src[offs[dst] + rank[i]] = src;
}

// ---- Kernel 5: fused score + softmax + aggregate. One wave per node. ----
// lane = slot*16 + sub; slot in [0,4) = edge slot, sub in [0,16): channels sub*8..+8.
// All channel math in f32x2 (v_pk_* f32); gathers via 32-bit byte offsets.
__global__ __launch_bounds__(256) void fused_aggr(const ushort_t* __restrict__ xl,
                                                  const ushort_t* __restrict__ xr,
                                                  const int* __restrict__ sorted_src,
                                                  const unsigned* __restrict__ offs,
                                                  const unsigned* __restrict__ counts,
                                                  const float* __restrict__ att,
                                                  const float* __restrict__ bias,
                                                  float* __restrict__ out) {
    const int tid = threadIdx.x;
    const int lane = tid & 63;
    int node = (blockIdx.x * 256 + tid) >> 6;
    node = __builtin_amdgcn_readfirstlane(node);
    const int slot = lane >> 4;
    const int sub  = lane & 15;
    const unsigned cb2 = (unsigned)sub * 16u;   // byte offset of this lane's 8 channels

    f32x2 attv[4], xrv[4];
    {
        const f32x2* ap = (const f32x2*)(att + sub * 8);
#pragma unroll
        for (int q = 0; q < 4; ++q) attv[q] = ap[q];
        const uint4 xv = *(const uint4*)((const char*)xr + (((unsigned)node << 8) + cb2));
        const unsigned* xw = (const unsigned*)&xv;
#pragma unroll
        for (int q = 0; q < 4; ++q) xrv[q] = bf2x2(xw[q]);
    }

    const int start = (int)offs[node];
    const int cnt   = (int)counts[node];
    const int rounds = (cnt + 3) >> 2;

    f32x2 acc2[4];
#pragma unroll
    for (int q = 0; q < 4; ++q) acc2[q] = (f32x2){0.f, 0.f};
    float d = 0.f;

    for (int r = 0; r < rounds; ++r) {
        const int k = r * 4 + slot;
        const bool valid = k < cnt;
        const int src = sorted_src[start + (valid ? k : 0)];
        const uint4 v = *(const uint4*)((const char*)xl + (((unsigned)src << 8) + cb2));
        const unsigned* vw = (const unsigned*)&v;
        f32x2 a2[4];
        f32x2 p2 = (f32x2){0.f, 0.f};
#pragma unroll
        for (int q = 0; q < 4; ++q) {
            a2[q] = bf2x2(vw[q]);
            f32x2 z = a2[q] + xrv[q];
            z = pkmax(z, z * NEG_SLOPE);
            p2 += attv[q] * z;
        }
        float p = p2.x + p2.y;
        p += __shfl_xor(p, 1);
        p += __shfl_xor(p, 2);
        p += __shfl_xor(p, 4);
        const float e = valid ? __expf(p) : 0.f;
        d += e;
        const f32x2 ev = (f32x2){e, e};
#pragma unroll
        for (int q = 0; q < 4; ++q) acc2[q] += ev * a2[q];
    }

    // reduce across the 4 edge slots (xor 16, 32)
#pragma unroll
    for (int off = 16; off <= 32; off <<= 1) {
        d += __shfl_xor(d, off);
#pragma unroll
        for (int q = 0; q < 4; ++q) {
            acc2[q].x += __shfl_xor(acc2[q].x, off);
            acc2[q].y += __shfl_xor(acc2[q].y, off);
        }
    }

    if (slot == 0) {
        const float inv = 1.f / d;
        const f32x2* bp = (const f32x2*)(bias + sub * 8);
        float4 o0, o1;
        o0.x = acc2[0].x * inv + bp[0].x; o0.y = acc2[0].y * inv + bp[0].y;
        o0.z = acc2[1].x * inv + bp[1].x; o0.w = acc2[1].y * inv + bp[1].y;
        o1.x = acc2[2].x * inv + bp[2].x; o1.y = acc2[2].y * inv + bp[2].y;
        o1.z = acc2[3].x * inv + bp[3].x; o1.w = acc2[3].y * inv + bp[3].y;
        float* op = out + (size_t)node * HC + sub * 8;
        *(float4*)op = o0;
        *(float4*)(op + 4) = o1;
    }
}

extern "C" void kernel_launch(void* const* d_in, const int* in_sizes, int n_in,
                              void* d_out, int out_size, void* d_ws, size_t ws_size,
                              hipStream_t stream) {
    const float* x    = (const float*)d_in[0];
    const int*   ei   = (const int*)d_in[1];
    const float* Wl   = (const float*)d_in[2];
    const float* Wr   = (const float*)d_in[3];
    const float* att  = (const float*)d_in[4];
    const float* bias = (const float*)d_in[5];
    float* out = (float*)d_out;

    const int E  = in_sizes[1] / 2;
    const int ET = E + T_NODES;

    // workspace layout
    ushort_t* xl = (ushort_t*)d_ws;                        // T*128 bf16
    ushort_t* xr = xl + (size_t)T_NODES * HC;              // T*128 bf16
    int* sorted_src = (int*)(xr + (size_t)T_NODES * HC);   // ET int
    unsigned* counts   = (unsigned*)(sorted_src + ET);     // T
    unsigned* offs     = counts + T_NODES;                 // T
    unsigned* partials = offs + T_NODES;                   // 128
    ushort_t* rank     = (ushort_t*)(partials + 128);      // ET u16
    uint4* wt          = (uint4*)(rank + ((ET + 7) & ~7)); // 32 KB, 16B-aligned

    prep_init<<<72, 256, 0, stream>>>(Wl, Wr, wt, counts, partials);

    const int histBlocks = (ET + 1023) / 1024;
    gemm_hist<<<histBlocks + GEMM_BLOCKS, 256, 0, stream>>>(x, wt, xl, xr,
                                                            ei, counts, rank,
                                                            E, ET, histBlocks);

    scan_all<<<T_NODES / 1024, 256, 0, stream>>>(counts, offs, partials);
    int eblocks = (ET + 255) / 256;
    scatter_edges<<<eblocks, 256, 0, stream>>>(ei, offs, rank, sorted_src, E, ET);

    fused_aggr<<<T_NODES / 4, 256, 0, stream>>>(xl, xr, sorted_src, offs, counts,
                                                att, bias, out);
}